// Round 15
// baseline (74.306 us; speedup 1.0000x reference)
//
#include <hip/hip_runtime.h>

typedef __attribute__((ext_vector_type(8))) short bf16x8;
typedef __attribute__((ext_vector_type(4))) float f32x4;
typedef __attribute__((ext_vector_type(2))) long long2v;
typedef unsigned int u32;
typedef unsigned long long u64;

#define LOG2E 1.44269504088896f

__device__ __forceinline__ short f2bf(float f) {
    union { float f; unsigned u; } v; v.f = f;
    unsigned r = v.u + 0x7fffu + ((v.u >> 16) & 1u);
    return (short)(r >> 16);
}

// float -> OCP e4m3fn byte (RNE, saturate to 448)
__device__ __forceinline__ u32 f2e4m3(float f) {
    u32 u = __float_as_uint(f);
    u32 sgn = (u >> 24) & 0x80u;
    u32 mag = u & 0x7fffffffu;
    if (mag >= 0x43E00000u) return sgn | 0x7Eu;
    if (mag < 0x3C800000u) {
        u32 q = (u32)(__uint_as_float(mag) * 512.0f + 0.5f);
        return sgn | q;
    }
    u32 r = mag + 0x0007FFFFu + ((mag >> 20) & 1u);
    u32 e8 = ((r >> 23) - 120u) & 0xFu;
    u32 m3 = (r >> 20) & 7u;
    return sgn | (e8 << 3) | m3;
}

__device__ __forceinline__ long pack8_e4m3(float4 a, float4 b) {
    u32 lo = f2e4m3(a.x) | (f2e4m3(a.y) << 8) | (f2e4m3(a.z) << 16) | (f2e4m3(a.w) << 24);
    u32 hi = f2e4m3(b.x) | (f2e4m3(b.y) << 8) | (f2e4m3(b.z) << 16) | (f2e4m3(b.w) << 24);
    return (long)(((u64)hi << 32) | lo);
}

#if __has_builtin(__builtin_amdgcn_exp2f)
#define EXP2(x) __builtin_amdgcn_exp2f(x)
#else
#define EXP2(x) __builtin_exp2f(x)
#endif

__device__ __forceinline__ u32 pack_bf16_trunc(float lo, float hi) {
#if __has_builtin(__builtin_amdgcn_perm)
    return __builtin_amdgcn_perm(__float_as_uint(hi), __float_as_uint(lo), 0x07060302u);
#else
    return (__float_as_uint(hi) & 0xFFFF0000u) | (__float_as_uint(lo) >> 16);
#endif
}

__device__ __forceinline__ void gload16(const void* g, void* l) {
    __builtin_amdgcn_global_load_lds(
        (const __attribute__((address_space(1))) void*)g,
        (__attribute__((address_space(3))) void*)l, 16, 0, 0);
}

// ---------------- prep (verbatim r13/r14; magnitude-verified) ----------------
// bid 0..255  : 2-fold tables, permuted slot ((c*2+h)*4+g)*4+j for center
//               m = c*32+8g+4h+j: nscs=-s*||c||^2*L, ts=2s*L
// bid 256..319: centers -> cfrag8, 16B slots [c][ks][lane] = {A0(h=0), A1(h=1)}
// bid 320..383: W -> wfrag (bf16) PV B-frag [c][ot][lane]: o=ot*16+l15, k=c*32+(l>>4)*8
__global__ __launch_bounds__(256) void rbf_prep(
    const float* __restrict__ centers, const float* __restrict__ sigmas,
    const float* __restrict__ W,
    char* __restrict__ cfrag8, short* __restrict__ wfrag,
    float* __restrict__ nscsp, float* __restrict__ tsp)
{
    const int tid = threadIdx.x;
    const int bid = blockIdx.x;
    if (bid < 256) {
        const int lane = tid & 63, w = tid >> 6;
        const int m = bid * 4 + w;
        const float4 v = ((const float4*)(centers + (size_t)m * 256))[lane];
        float s = v.x*v.x + v.y*v.y + v.z*v.z + v.w*v.w;
        #pragma unroll
        for (int off = 32; off >= 1; off >>= 1) s += __shfl_xor(s, off, 64);
        if (lane == 0) {
            const float sg = sigmas[m];
            const int c = m >> 5, w5 = m & 31;
            const int g = w5 >> 3, r = w5 & 7, h = r >> 2, j = r & 3;
            const int slot = ((c * 2 + h) * 4 + g) * 4 + j;
            nscsp[slot] = -sg * s * LOG2E;
            tsp[slot]   = 2.0f * sg * LOG2E;
        }
    } else if (bid < 320) {
        const int s = (bid - 256) * 256 + tid;               // 0..16383 (16B slots)
        const int c = s >> 9, ks = (s >> 6) & 7, lane = s & 63;
        const int l15 = lane & 15;
        const int k = ks * 32 + (lane >> 4) * 8;
        long2v t;
        #pragma unroll
        for (int h = 0; h < 2; ++h) {
            const int m = c * 32 + 8 * (l15 >> 2) + 4 * h + (l15 & 3);
            const float4 a = *(const float4*)(centers + (size_t)m * 256 + k);
            const float4 b = *(const float4*)(centers + (size_t)m * 256 + k + 4);
            t[h] = pack8_e4m3(a, b);
        }
        *(long2v*)(cfrag8 + (size_t)s * 16) = t;
    } else {
        const int s = (bid - 320) * 256 + tid;               // 0..16383
        const int c = s >> 9, ot = (s >> 6) & 7, lane = s & 63;
        const int o = ot * 16 + (lane & 15);
        const int k = c * 32 + (lane >> 4) * 8;
        const float4 a = *(const float4*)(W + (size_t)o * 1024 + k);
        const float4 b = *(const float4*)(W + (size_t)o * 1024 + k + 4);
        bf16x8 t;
        t[0]=f2bf(a.x); t[1]=f2bf(a.y); t[2]=f2bf(a.z); t[3]=f2bf(a.w);
        t[4]=f2bf(b.x); t[5]=f2bf(b.y); t[6]=f2bf(b.z); t[7]=f2bf(b.w);
        ((bf16x8*)wfrag)[s] = t;
    }
}

// ---------------- main: 2-wave blocks, 4 staggered barrier domains/CU ----------------
// 1024 blocks x 128 threads (2 waves x 32 rows). LDS 32KB (ring-3 C + tables)
// -> 4 blocks/CU resident; same 8 waves/CU as r12/r14 but in 4 independent
// barrier domains that stagger phases across the CU's pipes. Zero explicit
// drains: W-loads (issued before STAGE) force in-order retirement of chunk
// c+1's DMA at PV's compiler wait; pre-barrier vmcnt(4) is a no-op guard.
__global__ __launch_bounds__(128, 2) void rbf_main(
    const float* __restrict__ x, const float* __restrict__ bvec,
    const char* __restrict__ cfrag8, const short* __restrict__ wfrag,
    const float* __restrict__ nscsp, const float* __restrict__ tsp,
    float* __restrict__ out)
{
    __shared__ char   Cb8[3][8192];   // ring-3: [ks][lane]16B = ks*1024 + lane*16
    __shared__ float4 Tls[512];       // 8 KB: [0..255]=nscs, [256..511]=ts (permuted)

    const int tid = threadIdx.x;
    const int lane = tid & 63;
    const int l15 = lane & 15;
    const int g4 = lane >> 4;
    const int w = tid >> 6;                   // 0..1
    const int qb = blockIdx.x * 64 + w * 32;  // 32 rows per wave (2x 16-row tiles)

    // wave w stages ks = w*4 .. w*4+3 (4 KB) of the 8 KB chunk
#define STAGE(ci, slot) do {                                                       \
        const char* _cs = cfrag8 + (size_t)(ci) * 8192 + w * 4096 + lane * 16;     \
        gload16(_cs,        &Cb8[(slot)][w * 4096]);                               \
        gload16(_cs + 1024, &Cb8[(slot)][w * 4096 + 1024]);                        \
        gload16(_cs + 2048, &Cb8[(slot)][w * 4096 + 2048]);                        \
        gload16(_cs + 3072, &Cb8[(slot)][w * 4096 + 3072]);                        \
    } while (0)

// S + exp + pack for one chunk (both 16-row tiles) -> pa0, pa1 (r14-verified body)
#define SEXP(slot, cc, pa0, pa1) do {                                              \
        f32x4 s00 = (f32x4){0.f,0.f,0.f,0.f}, s01 = s00, s10 = s00, s11 = s00;     \
        const char* cb = &Cb8[(slot)][0] + (size_t)lane * 16;                      \
        __builtin_amdgcn_s_setprio(1);                                             \
        _Pragma("unroll")                                                          \
        for (int ks = 0; ks < 8; ++ks) {                                           \
            const long2v A = *(const long2v*)(cb + ks * 1024);                     \
            s00 = __builtin_amdgcn_mfma_f32_16x16x32_fp8_fp8(A[0], xq8[0][ks], s00, 0, 0, 0); \
            s10 = __builtin_amdgcn_mfma_f32_16x16x32_fp8_fp8(A[0], xq8[1][ks], s10, 0, 0, 0); \
            s01 = __builtin_amdgcn_mfma_f32_16x16x32_fp8_fp8(A[1], xq8[0][ks], s01, 0, 0, 0); \
            s11 = __builtin_amdgcn_mfma_f32_16x16x32_fp8_fp8(A[1], xq8[1][ks], s11, 0, 0, 0); \
        }                                                                          \
        __builtin_amdgcn_s_setprio(0);                                             \
        const int base0 = ((cc) * 2 + 0) * 4 + g4;                                 \
        const int base1 = ((cc) * 2 + 1) * 4 + g4;                                 \
        const float4 q0 = Tls[base0];                                              \
        const float4 t0 = Tls[256 + base0];                                        \
        const float4 q1 = Tls[base1];                                              \
        const float4 t1 = Tls[256 + base1];                                        \
        const float* q0p = (const float*)&q0; const float* t0p = (const float*)&t0;\
        const float* q1p = (const float*)&q1; const float* t1p = (const float*)&t1;\
        float p00[4], p01[4], p10[4], p11[4];                                      \
        _Pragma("unroll")                                                          \
        for (int j = 0; j < 4; ++j) {                                              \
            p00[j] = EXP2(fmaf(t0p[j], s00[j] - hxs0, q0p[j]));                    \
            p01[j] = EXP2(fmaf(t1p[j], s01[j] - hxs0, q1p[j]));                    \
            p10[j] = EXP2(fmaf(t0p[j], s10[j] - hxs1, q0p[j]));                    \
            p11[j] = EXP2(fmaf(t1p[j], s11[j] - hxs1, q1p[j]));                    \
        }                                                                          \
        pa0.u[0] = pack_bf16_trunc(p00[0], p00[1]);                                \
        pa0.u[1] = pack_bf16_trunc(p00[2], p00[3]);                                \
        pa0.u[2] = pack_bf16_trunc(p01[0], p01[1]);                                \
        pa0.u[3] = pack_bf16_trunc(p01[2], p01[3]);                                \
        pa1.u[0] = pack_bf16_trunc(p10[0], p10[1]);                                \
        pa1.u[1] = pack_bf16_trunc(p10[2], p10[3]);                                \
        pa1.u[2] = pack_bf16_trunc(p11[0], p11[1]);                                \
        pa1.u[3] = pack_bf16_trunc(p11[2], p11[3]);                                \
    } while (0)

#define PV(pa0, pa1, wv) do {                                                      \
        __builtin_amdgcn_s_setprio(1);                                             \
        _Pragma("unroll")                                                          \
        for (int ot = 0; ot < 8; ++ot) {                                           \
            acc[0][ot] = __builtin_amdgcn_mfma_f32_16x16x32_bf16(pa0.v, wv[ot], acc[0][ot], 0, 0, 0); \
            acc[1][ot] = __builtin_amdgcn_mfma_f32_16x16x32_bf16(pa1.v, wv[ot], acc[1][ot], 0, 0, 0); \
        }                                                                          \
        __builtin_amdgcn_s_setprio(0);                                             \
    } while (0)

    // ---- prologue: stage chunks 0,1; tables -> LDS; X -> fp8 regs ----
    STAGE(0, 0);
    STAGE(1, 1);

    Tls[tid]       = ((const float4*)nscsp)[tid];
    Tls[128 + tid] = ((const float4*)nscsp)[128 + tid];
    Tls[256 + tid] = ((const float4*)tsp)[tid];
    Tls[384 + tid] = ((const float4*)tsp)[128 + tid];

    long xq8[2][8];
    float xs[2];
    #pragma unroll
    for (int t = 0; t < 2; ++t) {
        const float* xr = x + (size_t)(qb + t * 16 + l15) * 256 + g4 * 8;
        float ss = 0.f;
        #pragma unroll
        for (int ks = 0; ks < 8; ++ks) {
            const float4 a = *(const float4*)(xr + ks * 32);
            const float4 b = *(const float4*)(xr + ks * 32 + 4);
            ss += a.x*a.x + a.y*a.y + a.z*a.z + a.w*a.w
                + b.x*b.x + b.y*b.y + b.z*b.z + b.w*b.w;
            xq8[t][ks] = pack8_e4m3(a, b);
        }
        ss += __shfl_xor(ss, 16, 64);
        ss += __shfl_xor(ss, 32, 64);
        xs[t] = ss;
    }
    const float hxs0 = 0.5f * xs[0];
    const float hxs1 = 0.5f * xs[1];

    f32x4 acc[2][8];
    #pragma unroll
    for (int t = 0; t < 2; ++t)
        #pragma unroll
        for (int ot = 0; ot < 8; ++ot) acc[t][ot] = (f32x4){0.f, 0.f, 0.f, 0.f};

    __syncthreads();   // prologue-only full drain

    const bf16x8* wsrc = (const bf16x8*)wfrag + lane;

    for (int c = 0; c < 32; ++c) {
        const int slot = c % 3;

        // W(c) -> regs FIRST (in-order vmcnt: waiting on these retires chunk
        // c+1's DMA from last iter, while c+2's DMA below stays outstanding)
        bf16x8 wv[8];
        #pragma unroll
        for (int f = 0; f < 8; ++f) wv[f] = wsrc[(size_t)c * 512 + f * 64];

        if (c < 30) STAGE(c + 2, (c + 2) % 3);

        union { u32 u[4]; bf16x8 v; } pa0, pa1;
        SEXP(slot, c, pa0, pa1);
        PV(pa0, pa1, wv);

        if (c < 31) {
            asm volatile("s_waitcnt vmcnt(4)" ::: "memory");  // guard: own c+2 DMA may fly
            __builtin_amdgcn_s_barrier();
        }
    }

    // ---- epilogue: D layout col=l15 (o-sub), row=g4*4+jr (q-sub) ----
    #pragma unroll
    for (int t = 0; t < 2; ++t) {
        #pragma unroll
        for (int jr = 0; jr < 4; ++jr) {
            const int q = qb + t * 16 + g4 * 4 + jr;
            #pragma unroll
            for (int ot = 0; ot < 8; ++ot)
                out[(size_t)q * 128 + ot * 16 + l15] = acc[t][ot][jr] + bvec[ot * 16 + l15];
        }
    }
#undef STAGE
#undef SEXP
#undef PV
}

extern "C" void kernel_launch(void* const* d_in, const int* in_sizes, int n_in,
                              void* d_out, int out_size, void* d_ws, size_t ws_size,
                              hipStream_t stream) {
    (void)in_sizes; (void)n_in; (void)out_size; (void)ws_size;
    const float* x       = (const float*)d_in[0];
    const float* centers = (const float*)d_in[1];
    const float* sigmas  = (const float*)d_in[2];
    const float* W       = (const float*)d_in[3];
    const float* b       = (const float*)d_in[4];
    float* out = (float*)d_out;

    char*  cfrag8 = (char*)d_ws;                     // 16384 slots * 16B = 256 KB
    short* wfrag  = (short*)(cfrag8 + 16384 * 16);   // 16384 slots * 16B = 256 KB
    float* nscsp  = (float*)(wfrag + 16384 * 8);     // 4 KB
    float* tsp    = nscsp + 1024;                    // 4 KB

    rbf_prep<<<384, 256, 0, stream>>>(centers, sigmas, W, cfrag8, wfrag, nscsp, tsp);
    rbf_main<<<1024, 128, 0, stream>>>(x, b, cfrag8, wfrag, nscsp, tsp, out);
}

// Round 16
// 70.508 us; speedup vs baseline: 1.0539x; 1.0539x over previous
//
#include <hip/hip_runtime.h>

typedef __attribute__((ext_vector_type(8))) short bf16x8;
typedef __attribute__((ext_vector_type(4))) float f32x4;
typedef __attribute__((ext_vector_type(2))) long long2v;
typedef unsigned int u32;
typedef unsigned long long u64;

#define LOG2E 1.44269504088896f

__device__ __forceinline__ short f2bf(float f) {
    union { float f; unsigned u; } v; v.f = f;
    unsigned r = v.u + 0x7fffu + ((v.u >> 16) & 1u);
    return (short)(r >> 16);
}

// float -> OCP e4m3fn byte (RNE, saturate to 448)
__device__ __forceinline__ u32 f2e4m3(float f) {
    u32 u = __float_as_uint(f);
    u32 sgn = (u >> 24) & 0x80u;
    u32 mag = u & 0x7fffffffu;
    if (mag >= 0x43E00000u) return sgn | 0x7Eu;
    if (mag < 0x3C800000u) {
        u32 q = (u32)(__uint_as_float(mag) * 512.0f + 0.5f);
        return sgn | q;
    }
    u32 r = mag + 0x0007FFFFu + ((mag >> 20) & 1u);
    u32 e8 = ((r >> 23) - 120u) & 0xFu;
    u32 m3 = (r >> 20) & 7u;
    return sgn | (e8 << 3) | m3;
}

__device__ __forceinline__ long pack8_e4m3(float4 a, float4 b) {
    u32 lo = f2e4m3(a.x) | (f2e4m3(a.y) << 8) | (f2e4m3(a.z) << 16) | (f2e4m3(a.w) << 24);
    u32 hi = f2e4m3(b.x) | (f2e4m3(b.y) << 8) | (f2e4m3(b.z) << 16) | (f2e4m3(b.w) << 24);
    return (long)(((u64)hi << 32) | lo);
}

#if __has_builtin(__builtin_amdgcn_exp2f)
#define EXP2(x) __builtin_amdgcn_exp2f(x)
#else
#define EXP2(x) __builtin_exp2f(x)
#endif

__device__ __forceinline__ u32 pack_bf16_trunc(float lo, float hi) {
#if __has_builtin(__builtin_amdgcn_perm)
    return __builtin_amdgcn_perm(__float_as_uint(hi), __float_as_uint(lo), 0x07060302u);
#else
    return (__float_as_uint(hi) & 0xFFFF0000u) | (__float_as_uint(lo) >> 16);
#endif
}

__device__ __forceinline__ void gload16(const void* g, void* l) {
    __builtin_amdgcn_global_load_lds(
        (const __attribute__((address_space(1))) void*)g,
        (__attribute__((address_space(3))) void*)l, 16, 0, 0);
}

// ---------------- prep (verbatim r13/r14; verified) ----------------
// bid 0..255  : 2-fold tables, permuted slot ((c*2+h)*4+g)*4+j for center
//               m = c*32+8g+4h+j: nscs=-s*||c||^2*L, ts=2s*L
// bid 256..319: centers -> cfrag8, 16B slots [c][ks][lane] = {A0(h=0), A1(h=1)}
// bid 320..383: W -> wfrag (bf16) PV B-frag [c][ot][lane]: o=ot*16+l15, k=c*32+(l>>4)*8
__global__ __launch_bounds__(256) void rbf_prep(
    const float* __restrict__ centers, const float* __restrict__ sigmas,
    const float* __restrict__ W,
    char* __restrict__ cfrag8, short* __restrict__ wfrag,
    float* __restrict__ nscsp, float* __restrict__ tsp)
{
    const int tid = threadIdx.x;
    const int bid = blockIdx.x;
    if (bid < 256) {
        const int lane = tid & 63, w = tid >> 6;
        const int m = bid * 4 + w;
        const float4 v = ((const float4*)(centers + (size_t)m * 256))[lane];
        float s = v.x*v.x + v.y*v.y + v.z*v.z + v.w*v.w;
        #pragma unroll
        for (int off = 32; off >= 1; off >>= 1) s += __shfl_xor(s, off, 64);
        if (lane == 0) {
            const float sg = sigmas[m];
            const int c = m >> 5, w5 = m & 31;
            const int g = w5 >> 3, r = w5 & 7, h = r >> 2, j = r & 3;
            const int slot = ((c * 2 + h) * 4 + g) * 4 + j;
            nscsp[slot] = -sg * s * LOG2E;
            tsp[slot]   = 2.0f * sg * LOG2E;
        }
    } else if (bid < 320) {
        const int s = (bid - 256) * 256 + tid;               // 0..16383 (16B slots)
        const int c = s >> 9, ks = (s >> 6) & 7, lane = s & 63;
        const int l15 = lane & 15;
        const int k = ks * 32 + (lane >> 4) * 8;
        long2v t;
        #pragma unroll
        for (int h = 0; h < 2; ++h) {
            const int m = c * 32 + 8 * (l15 >> 2) + 4 * h + (l15 & 3);
            const float4 a = *(const float4*)(centers + (size_t)m * 256 + k);
            const float4 b = *(const float4*)(centers + (size_t)m * 256 + k + 4);
            t[h] = pack8_e4m3(a, b);
        }
        *(long2v*)(cfrag8 + (size_t)s * 16) = t;
    } else {
        const int s = (bid - 320) * 256 + tid;               // 0..16383
        const int c = s >> 9, ot = (s >> 6) & 7, lane = s & 63;
        const int o = ot * 16 + (lane & 15);
        const int k = c * 32 + (lane >> 4) * 8;
        const float4 a = *(const float4*)(W + (size_t)o * 1024 + k);
        const float4 b = *(const float4*)(W + (size_t)o * 1024 + k + 4);
        bf16x8 t;
        t[0]=f2bf(a.x); t[1]=f2bf(a.y); t[2]=f2bf(a.z); t[3]=f2bf(a.w);
        t[4]=f2bf(b.x); t[5]=f2bf(b.y); t[6]=f2bf(b.z); t[7]=f2bf(b.w);
        ((bf16x8*)wfrag)[s] = t;
    }
}

// ---------------- main: r14 base + register A-lookahead (zero-latency S-phase) ----------------
// 512 blocks x 256 threads (4 fat waves), 2 blocks/CU, ring-4 C slots + tables
// (40 KB). Chunk c consumes A-frags prefetched into REGISTERS during chunk c-1;
// staging runs 3 chunks ahead so the prefetched slot's DMA is provably retired
// by the previous iteration's W-load wait (in-order vmcnt). Unroll-2 gives the
// two A-register sets static names (rX even chunks, rY odd). One barrier/chunk,
// counted vmcnt(2) guard only.
__global__ __launch_bounds__(256, 2) void rbf_main(
    const float* __restrict__ x, const float* __restrict__ bvec,
    const char* __restrict__ cfrag8, const short* __restrict__ wfrag,
    const float* __restrict__ nscsp, const float* __restrict__ tsp,
    float* __restrict__ out)
{
    __shared__ char   Cb8[4][8192];   // ring-4: chunk c -> slot c&3; [ks][lane]16B
    __shared__ float4 Tls[512];       // 8 KB: [0..255]=nscs, [256..511]=ts (permuted)

    const int tid = threadIdx.x;
    const int lane = tid & 63;
    const int l15 = lane & 15;
    const int g4 = lane >> 4;
    const int w = tid >> 6;                    // 0..3
    const int qb = blockIdx.x * 128 + w * 32;  // 32 rows per wave (2x 16-row tiles)

#define STAGE(ci, slot) do {                                                       \
        const char* _cs = cfrag8 + (size_t)(ci) * 8192 + w * 2048 + lane * 16;     \
        gload16(_cs,        &Cb8[(slot)][w * 2048]);                               \
        gload16(_cs + 1024, &Cb8[(slot)][w * 2048 + 1024]);                        \
    } while (0)

#define PREF(ci, rv) do {                                                          \
        const char* _cb = &Cb8[(ci) & 3][0] + (size_t)lane * 16;                   \
        _Pragma("unroll")                                                          \
        for (int ks = 0; ks < 8; ++ks) rv[ks] = *(const long2v*)(_cb + ks * 1024); \
    } while (0)

// S + exp + pack from REGISTER A-frags (math identical to r14's verified body)
#define SEXPR(rv, cc, pa0, pa1) do {                                               \
        f32x4 s00 = (f32x4){0.f,0.f,0.f,0.f}, s01 = s00, s10 = s00, s11 = s00;     \
        _Pragma("unroll")                                                          \
        for (int ks = 0; ks < 8; ++ks) {                                           \
            s00 = __builtin_amdgcn_mfma_f32_16x16x32_fp8_fp8(rv[ks][0], xq8[0][ks], s00, 0, 0, 0); \
            s10 = __builtin_amdgcn_mfma_f32_16x16x32_fp8_fp8(rv[ks][0], xq8[1][ks], s10, 0, 0, 0); \
            s01 = __builtin_amdgcn_mfma_f32_16x16x32_fp8_fp8(rv[ks][1], xq8[0][ks], s01, 0, 0, 0); \
            s11 = __builtin_amdgcn_mfma_f32_16x16x32_fp8_fp8(rv[ks][1], xq8[1][ks], s11, 0, 0, 0); \
        }                                                                          \
        const int base0 = ((cc) * 2 + 0) * 4 + g4;                                 \
        const int base1 = ((cc) * 2 + 1) * 4 + g4;                                 \
        const float4 q0 = Tls[base0];                                              \
        const float4 t0 = Tls[256 + base0];                                        \
        const float4 q1 = Tls[base1];                                              \
        const float4 t1 = Tls[256 + base1];                                        \
        const float* q0p = (const float*)&q0; const float* t0p = (const float*)&t0;\
        const float* q1p = (const float*)&q1; const float* t1p = (const float*)&t1;\
        float p00[4], p01[4], p10[4], p11[4];                                      \
        _Pragma("unroll")                                                          \
        for (int j = 0; j < 4; ++j) {                                              \
            p00[j] = EXP2(fmaf(t0p[j], s00[j] - hxs0, q0p[j]));                    \
            p01[j] = EXP2(fmaf(t1p[j], s01[j] - hxs0, q1p[j]));                    \
            p10[j] = EXP2(fmaf(t0p[j], s10[j] - hxs1, q0p[j]));                    \
            p11[j] = EXP2(fmaf(t1p[j], s11[j] - hxs1, q1p[j]));                    \
        }                                                                          \
        pa0.u[0] = pack_bf16_trunc(p00[0], p00[1]);                                \
        pa0.u[1] = pack_bf16_trunc(p00[2], p00[3]);                                \
        pa0.u[2] = pack_bf16_trunc(p01[0], p01[1]);                                \
        pa0.u[3] = pack_bf16_trunc(p01[2], p01[3]);                                \
        pa1.u[0] = pack_bf16_trunc(p10[0], p10[1]);                                \
        pa1.u[1] = pack_bf16_trunc(p10[2], p10[3]);                                \
        pa1.u[2] = pack_bf16_trunc(p11[0], p11[1]);                                \
        pa1.u[3] = pack_bf16_trunc(p11[2], p11[3]);                                \
    } while (0)

#define PVX(pa0, pa1, wv) do {                                                     \
        _Pragma("unroll")                                                          \
        for (int ot = 0; ot < 8; ++ot) {                                           \
            acc[0][ot] = __builtin_amdgcn_mfma_f32_16x16x32_bf16(pa0.v, wv[ot], acc[0][ot], 0, 0, 0); \
            acc[1][ot] = __builtin_amdgcn_mfma_f32_16x16x32_bf16(pa1.v, wv[ot], acc[1][ot], 0, 0, 0); \
        }                                                                          \
    } while (0)

// one chunk: W(c)->regs, stage c+3, prefetch A(c+1)->nxt, compute from cur
#define CHUNK(c, cur, nxt) do {                                                    \
        bf16x8 wv[8];                                                              \
        _Pragma("unroll")                                                          \
        for (int f = 0; f < 8; ++f) wv[f] = wsrc[(size_t)(c) * 512 + f * 64];      \
        if ((c) <= 28) STAGE((c) + 3, ((c) + 3) & 3);                              \
        if ((c) <= 30) PREF((c) + 1, nxt);                                         \
        union { u32 u[4]; bf16x8 v; } pa0, pa1;                                    \
        SEXPR(cur, (c), pa0, pa1);                                                 \
        PVX(pa0, pa1, wv);                                                         \
        if ((c) < 31) {                                                            \
            if ((c) <= 28) { asm volatile("s_waitcnt vmcnt(2)" ::: "memory"); }    \
            else           { asm volatile("s_waitcnt vmcnt(0)" ::: "memory"); }    \
            __builtin_amdgcn_s_barrier();                                          \
        }                                                                          \
    } while (0)

    // ---- prologue: stage chunks 0..2; tables -> LDS; X -> fp8 regs ----
    STAGE(0, 0);
    STAGE(1, 1);
    STAGE(2, 2);

    Tls[tid]       = ((const float4*)nscsp)[tid];
    Tls[256 + tid] = ((const float4*)tsp)[tid];

    long xq8[2][8];
    float xs[2];
    #pragma unroll
    for (int t = 0; t < 2; ++t) {
        const float* xr = x + (size_t)(qb + t * 16 + l15) * 256 + g4 * 8;
        float ss = 0.f;
        #pragma unroll
        for (int ks = 0; ks < 8; ++ks) {
            const float4 a = *(const float4*)(xr + ks * 32);
            const float4 b = *(const float4*)(xr + ks * 32 + 4);
            ss += a.x*a.x + a.y*a.y + a.z*a.z + a.w*a.w
                + b.x*b.x + b.y*b.y + b.z*b.z + b.w*b.w;
            xq8[t][ks] = pack8_e4m3(a, b);
        }
        ss += __shfl_xor(ss, 16, 64);
        ss += __shfl_xor(ss, 32, 64);
        xs[t] = ss;
    }
    const float hxs0 = 0.5f * xs[0];
    const float hxs1 = 0.5f * xs[1];

    f32x4 acc[2][8];
    #pragma unroll
    for (int t = 0; t < 2; ++t)
        #pragma unroll
        for (int ot = 0; ot < 8; ++ot) acc[t][ot] = (f32x4){0.f, 0.f, 0.f, 0.f};

    __syncthreads();   // prologue drain: chunks 0-2 DMA + tables + X

    const bf16x8* wsrc = (const bf16x8*)wfrag + lane;

    long2v rX[8], rY[8];
    PREF(0, rX);       // A(0): staged in prologue, fully drained

    #pragma unroll 2
    for (int i = 0; i < 16; ++i) {
        CHUNK(2 * i,     rX, rY);   // even chunk: consume rX, prefetch rY = A(2i+1)
        CHUNK(2 * i + 1, rY, rX);   // odd  chunk: consume rY, prefetch rX = A(2i+2)
    }

    // ---- epilogue: D layout col=l15 (o-sub), row=g4*4+jr (q-sub) ----
    #pragma unroll
    for (int t = 0; t < 2; ++t) {
        #pragma unroll
        for (int jr = 0; jr < 4; ++jr) {
            const int q = qb + t * 16 + g4 * 4 + jr;
            #pragma unroll
            for (int ot = 0; ot < 8; ++ot)
                out[(size_t)q * 128 + ot * 16 + l15] = acc[t][ot][jr] + bvec[ot * 16 + l15];
        }
    }
#undef STAGE
#undef PREF
#undef SEXPR
#undef PVX
#undef CHUNK
}

extern "C" void kernel_launch(void* const* d_in, const int* in_sizes, int n_in,
                              void* d_out, int out_size, void* d_ws, size_t ws_size,
                              hipStream_t stream) {
    (void)in_sizes; (void)n_in; (void)out_size; (void)ws_size;
    const float* x       = (const float*)d_in[0];
    const float* centers = (const float*)d_in[1];
    const float* sigmas  = (const float*)d_in[2];
    const float* W       = (const float*)d_in[3];
    const float* b       = (const float*)d_in[4];
    float* out = (float*)d_out;

    char*  cfrag8 = (char*)d_ws;                     // 16384 slots * 16B = 256 KB
    short* wfrag  = (short*)(cfrag8 + 16384 * 16);   // 16384 slots * 16B = 256 KB
    float* nscsp  = (float*)(wfrag + 16384 * 8);     // 4 KB
    float* tsp    = nscsp + 1024;                    // 4 KB

    rbf_prep<<<384, 256, 0, stream>>>(centers, sigmas, W, cfrag8, wfrag, nscsp, tsp);
    rbf_main<<<512, 256, 0, stream>>>(x, b, cfrag8, wfrag, nscsp, tsp, out);
}

// Round 17
// 68.238 us; speedup vs baseline: 1.0889x; 1.0333x over previous
//
#include <hip/hip_runtime.h>

typedef __attribute__((ext_vector_type(8))) short bf16x8;
typedef __attribute__((ext_vector_type(4))) float f32x4;
typedef __attribute__((ext_vector_type(2))) long long2v;
typedef __attribute__((ext_vector_type(8))) int i32x8;
typedef unsigned int u32;
typedef unsigned long long u64;

#define LOG2E 1.44269504088896f

__device__ __forceinline__ short f2bf(float f) {
    union { float f; unsigned u; } v; v.f = f;
    unsigned r = v.u + 0x7fffu + ((v.u >> 16) & 1u);
    return (short)(r >> 16);
}

// float -> OCP e4m3fn byte (RNE, saturate to 448)
__device__ __forceinline__ u32 f2e4m3(float f) {
    u32 u = __float_as_uint(f);
    u32 sgn = (u >> 24) & 0x80u;
    u32 mag = u & 0x7fffffffu;
    if (mag >= 0x43E00000u) return sgn | 0x7Eu;
    if (mag < 0x3C800000u) {
        u32 q = (u32)(__uint_as_float(mag) * 512.0f + 0.5f);
        return sgn | q;
    }
    u32 r = mag + 0x0007FFFFu + ((mag >> 20) & 1u);
    u32 e8 = ((r >> 23) - 120u) & 0xFu;
    u32 m3 = (r >> 20) & 7u;
    return sgn | (e8 << 3) | m3;
}

__device__ __forceinline__ long pack8_e4m3(float4 a, float4 b) {
    u32 lo = f2e4m3(a.x) | (f2e4m3(a.y) << 8) | (f2e4m3(a.z) << 16) | (f2e4m3(a.w) << 24);
    u32 hi = f2e4m3(b.x) | (f2e4m3(b.y) << 8) | (f2e4m3(b.z) << 16) | (f2e4m3(b.w) << 24);
    return (long)(((u64)hi << 32) | lo);
}

#if __has_builtin(__builtin_amdgcn_exp2f)
#define EXP2(x) __builtin_amdgcn_exp2f(x)
#else
#define EXP2(x) __builtin_exp2f(x)
#endif

__device__ __forceinline__ u32 pack_bf16_trunc(float lo, float hi) {
#if __has_builtin(__builtin_amdgcn_perm)
    return __builtin_amdgcn_perm(__float_as_uint(hi), __float_as_uint(lo), 0x07060302u);
#else
    return (__float_as_uint(hi) & 0xFFFF0000u) | (__float_as_uint(lo) >> 16);
#endif
}

__device__ __forceinline__ void gload16(const void* g, void* l) {
    __builtin_amdgcn_global_load_lds(
        (const __attribute__((address_space(1))) void*)g,
        (__attribute__((address_space(3))) void*)l, 16, 0, 0);
}

// K=128 fp8 MFMA: scaled (identity e8m0 scales = 0x7F -> 2^0, layout-proof) with
// fallback to 4x K=32 on the SAME data (A/B k-conventions are self-consistent).
#if __has_builtin(__builtin_amdgcn_mfma_scale_f32_16x16x128_f8f6f4)
#define MFMA128(A, B, C) \
    C = __builtin_amdgcn_mfma_scale_f32_16x16x128_f8f6f4((A), (B), (C), 0, 0, 0, 0x7F7F7F7F, 0, 0x7F7F7F7F)
#else
#define MFMA128(A, B, C) do {                                                      \
        union { i32x8 v; long l[4]; } _a, _b; _a.v = (A); _b.v = (B);              \
        _Pragma("unroll")                                                          \
        for (int _dp = 0; _dp < 4; ++_dp)                                          \
            C = __builtin_amdgcn_mfma_f32_16x16x32_fp8_fp8(_a.l[_dp], _b.l[_dp], (C), 0, 0, 0); \
    } while (0)
#endif

// ---------------- prep ----------------
// bid 0..255  : 2-fold tables, permuted slot ((c*2+h)*4+g)*4+j for center
//               m = c*32+8g+4h+j: nscs=-s*||c||^2*L, ts=2s*L   (unchanged)
// bid 256..319: centers -> cfrag8 for K=128 operands. 16B slot
//               s = c*512 + h2k*128 + piece*64 + lane  (h2k=h*2+ks):
//               byte j' (0..15) = fp8(centers[m][k]), m = c*32+8*(l15>>2)+4*h+(l15&3),
//               k = ks*128 + g4*32 + piece*16 + j'   (same conv as X packing)
// bid 320..383: W -> wfrag (bf16) PV B-frag [c][ot][lane]  (unchanged)
__global__ __launch_bounds__(256) void rbf_prep(
    const float* __restrict__ centers, const float* __restrict__ sigmas,
    const float* __restrict__ W,
    char* __restrict__ cfrag8, short* __restrict__ wfrag,
    float* __restrict__ nscsp, float* __restrict__ tsp)
{
    const int tid = threadIdx.x;
    const int bid = blockIdx.x;
    if (bid < 256) {
        const int lane = tid & 63, w = tid >> 6;
        const int m = bid * 4 + w;
        const float4 v = ((const float4*)(centers + (size_t)m * 256))[lane];
        float s = v.x*v.x + v.y*v.y + v.z*v.z + v.w*v.w;
        #pragma unroll
        for (int off = 32; off >= 1; off >>= 1) s += __shfl_xor(s, off, 64);
        if (lane == 0) {
            const float sg = sigmas[m];
            const int c = m >> 5, w5 = m & 31;
            const int g = w5 >> 3, r = w5 & 7, h = r >> 2, j = r & 3;
            const int slot = ((c * 2 + h) * 4 + g) * 4 + j;
            nscsp[slot] = -sg * s * LOG2E;
            tsp[slot]   = 2.0f * sg * LOG2E;
        }
    } else if (bid < 320) {
        const int s = (bid - 256) * 256 + tid;               // 0..16383 (16B slots)
        const int c = s >> 9, h2k = (s >> 7) & 3, piece = (s >> 6) & 1, lane = s & 63;
        const int h = h2k >> 1, ks = h2k & 1;
        const int l15 = lane & 15, g4 = lane >> 4;
        const int m = c * 32 + 8 * (l15 >> 2) + 4 * h + (l15 & 3);
        const int kb = ks * 128 + g4 * 32 + piece * 16;
        const float* cp = centers + (size_t)m * 256 + kb;
        const float4 a0 = *(const float4*)(cp);
        const float4 a1 = *(const float4*)(cp + 4);
        const float4 a2 = *(const float4*)(cp + 8);
        const float4 a3 = *(const float4*)(cp + 12);
        long2v t;
        t[0] = pack8_e4m3(a0, a1);
        t[1] = pack8_e4m3(a2, a3);
        *(long2v*)(cfrag8 + (size_t)s * 16) = t;
    } else {
        const int s = (bid - 320) * 256 + tid;               // 0..16383
        const int c = s >> 9, ot = (s >> 6) & 7, lane = s & 63;
        const int o = ot * 16 + (lane & 15);
        const int k = c * 32 + (lane >> 4) * 8;
        const float4 a = *(const float4*)(W + (size_t)o * 1024 + k);
        const float4 b = *(const float4*)(W + (size_t)o * 1024 + k + 4);
        bf16x8 t;
        t[0]=f2bf(a.x); t[1]=f2bf(a.y); t[2]=f2bf(a.z); t[3]=f2bf(a.w);
        t[4]=f2bf(b.x); t[5]=f2bf(b.y); t[6]=f2bf(b.z); t[7]=f2bf(b.w);
        ((bf16x8*)wfrag)[s] = t;
    }
}

// ---------------- main: r14 skeleton + K=128 S-phase (8 MFMAs/chunk, chain depth 2) ----------------
// 512 blocks x 256 threads (4 fat waves, 32 rows/wave), 2 blocks/CU, ring-4 C +
// tables (40 KB). Per chunk: W(c)->regs (VMEM), STAGE(c+3) (DMA), S via 4x
// (2x ds_read_b128 -> v8i32) + 8 scaled MFMAs, exp/pack (r14-verified), PV.
// Counted vmcnt guard only; one barrier/chunk.
__global__ __launch_bounds__(256, 2) void rbf_main(
    const float* __restrict__ x, const float* __restrict__ bvec,
    const char* __restrict__ cfrag8, const short* __restrict__ wfrag,
    const float* __restrict__ nscsp, const float* __restrict__ tsp,
    float* __restrict__ out)
{
    __shared__ char   Cb8[4][8192];   // ring-4: chunk c -> slot c&3; [h2k][piece][lane]16B
    __shared__ float4 Tls[512];       // 8 KB: [0..255]=nscs, [256..511]=ts (permuted)

    const int tid = threadIdx.x;
    const int lane = tid & 63;
    const int l15 = lane & 15;
    const int g4 = lane >> 4;
    const int w = tid >> 6;                    // 0..3
    const int qb = blockIdx.x * 128 + w * 32;  // 32 rows per wave (2x 16-row tiles)

#define STAGE(ci, slot) do {                                                       \
        const char* _cs = cfrag8 + (size_t)(ci) * 8192 + w * 2048 + lane * 16;     \
        gload16(_cs,        &Cb8[(slot)][w * 2048]);                               \
        gload16(_cs + 1024, &Cb8[(slot)][w * 2048 + 1024]);                        \
    } while (0)

#define Z4 (f32x4){0.f,0.f,0.f,0.f}

// S (K=128) + exp + pack; math identical to r14's verified body
#define SEXPR(slot, cc, pa0, pa1) do {                                             \
        const char* cb = &Cb8[(slot)][0] + (size_t)lane * 16;                      \
        union { long2v p[2]; i32x8 v; } A0, A1, A2, A3;                            \
        A0.p[0] = *(const long2v*)(cb);          A0.p[1] = *(const long2v*)(cb + 1024); \
        A1.p[0] = *(const long2v*)(cb + 2048);   A1.p[1] = *(const long2v*)(cb + 3072); \
        A2.p[0] = *(const long2v*)(cb + 4096);   A2.p[1] = *(const long2v*)(cb + 5120); \
        A3.p[0] = *(const long2v*)(cb + 6144);   A3.p[1] = *(const long2v*)(cb + 7168); \
        f32x4 s00 = Z4, s01 = Z4, s10 = Z4, s11 = Z4;                              \
        MFMA128(A0.v, xq00, s00);  MFMA128(A0.v, xq10, s10);                       \
        MFMA128(A1.v, xq01, s00);  MFMA128(A1.v, xq11, s10);                       \
        MFMA128(A2.v, xq00, s01);  MFMA128(A2.v, xq10, s11);                       \
        MFMA128(A3.v, xq01, s01);  MFMA128(A3.v, xq11, s11);                       \
        const int base0 = ((cc) * 2 + 0) * 4 + g4;                                 \
        const int base1 = ((cc) * 2 + 1) * 4 + g4;                                 \
        const float4 q0 = Tls[base0];                                              \
        const float4 t0 = Tls[256 + base0];                                        \
        const float4 q1 = Tls[base1];                                              \
        const float4 t1 = Tls[256 + base1];                                        \
        const float* q0p = (const float*)&q0; const float* t0p = (const float*)&t0;\
        const float* q1p = (const float*)&q1; const float* t1p = (const float*)&t1;\
        float p00[4], p01[4], p10[4], p11[4];                                      \
        _Pragma("unroll")                                                          \
        for (int j = 0; j < 4; ++j) {                                              \
            p00[j] = EXP2(fmaf(t0p[j], s00[j] - hxs0, q0p[j]));                    \
            p01[j] = EXP2(fmaf(t1p[j], s01[j] - hxs0, q1p[j]));                    \
            p10[j] = EXP2(fmaf(t0p[j], s10[j] - hxs1, q0p[j]));                    \
            p11[j] = EXP2(fmaf(t1p[j], s11[j] - hxs1, q1p[j]));                    \
        }                                                                          \
        pa0.u[0] = pack_bf16_trunc(p00[0], p00[1]);                                \
        pa0.u[1] = pack_bf16_trunc(p00[2], p00[3]);                                \
        pa0.u[2] = pack_bf16_trunc(p01[0], p01[1]);                                \
        pa0.u[3] = pack_bf16_trunc(p01[2], p01[3]);                                \
        pa1.u[0] = pack_bf16_trunc(p10[0], p10[1]);                                \
        pa1.u[1] = pack_bf16_trunc(p10[2], p10[3]);                                \
        pa1.u[2] = pack_bf16_trunc(p11[0], p11[1]);                                \
        pa1.u[3] = pack_bf16_trunc(p11[2], p11[3]);                                \
    } while (0)

#define PVX(pa0, pa1, wv) do {                                                     \
        _Pragma("unroll")                                                          \
        for (int ot = 0; ot < 8; ++ot) {                                           \
            acc[0][ot] = __builtin_amdgcn_mfma_f32_16x16x32_bf16(pa0.v, wv[ot], acc[0][ot], 0, 0, 0); \
            acc[1][ot] = __builtin_amdgcn_mfma_f32_16x16x32_bf16(pa1.v, wv[ot], acc[1][ot], 0, 0, 0); \
        }                                                                          \
    } while (0)

    // ---- prologue: stage chunks 0..2; tables -> LDS; X -> fp8 K=128 operands ----
    STAGE(0, 0);
    STAGE(1, 1);
    STAGE(2, 2);

    Tls[tid]       = ((const float4*)nscsp)[tid];
    Tls[256 + tid] = ((const float4*)tsp)[tid];

    i32x8 xq00, xq01, xq10, xq11;   // [tile][kslice]
    float xs[2];
    #pragma unroll
    for (int t = 0; t < 2; ++t) {
        const float* xr = x + (size_t)(qb + t * 16 + l15) * 256;
        float ss = 0.f;
        #pragma unroll
        for (int ks = 0; ks < 2; ++ks) {
            union { long lg[4]; i32x8 v; } xx;
            const float* xb = xr + ks * 128 + g4 * 32;
            #pragma unroll
            for (int q8 = 0; q8 < 4; ++q8) {
                const float4 a = *(const float4*)(xb + q8 * 8);
                const float4 b = *(const float4*)(xb + q8 * 8 + 4);
                ss += a.x*a.x + a.y*a.y + a.z*a.z + a.w*a.w
                    + b.x*b.x + b.y*b.y + b.z*b.z + b.w*b.w;
                xx.lg[q8] = pack8_e4m3(a, b);
            }
            if (t == 0) { if (ks == 0) xq00 = xx.v; else xq01 = xx.v; }
            else        { if (ks == 0) xq10 = xx.v; else xq11 = xx.v; }
        }
        ss += __shfl_xor(ss, 16, 64);
        ss += __shfl_xor(ss, 32, 64);
        xs[t] = ss;
    }
    const float hxs0 = 0.5f * xs[0];
    const float hxs1 = 0.5f * xs[1];

    f32x4 acc[2][8];
    #pragma unroll
    for (int t = 0; t < 2; ++t)
        #pragma unroll
        for (int ot = 0; ot < 8; ++ot) acc[t][ot] = Z4;

    __syncthreads();   // prologue drain: chunks 0-2 DMA + tables + X

    const bf16x8* wsrc = (const bf16x8*)wfrag + lane;

    for (int c = 0; c < 32; ++c) {
        const int slot = c & 3;

        // W(c) -> regs first (older than STAGE in vmcnt order: compiler's W-wait
        // leaves the newer STAGE outstanding; prior iters' STAGEs retire with it)
        bf16x8 wv[8];
        #pragma unroll
        for (int f = 0; f < 8; ++f) wv[f] = wsrc[(size_t)c * 512 + f * 64];

        if (c <= 28) STAGE(c + 3, (c + 3) & 3);

        union { u32 u[4]; bf16x8 v; } pa0, pa1;
        SEXPR(slot, c, pa0, pa1);
        PVX(pa0, pa1, wv);

        if (c < 31) {
            if (c <= 28) { asm volatile("s_waitcnt vmcnt(2)" ::: "memory"); }
            else         { asm volatile("s_waitcnt vmcnt(0)" ::: "memory"); }
            __builtin_amdgcn_s_barrier();
        }
    }

    // ---- epilogue: D layout col=l15 (o-sub), row=g4*4+jr (q-sub) ----
    #pragma unroll
    for (int t = 0; t < 2; ++t) {
        #pragma unroll
        for (int jr = 0; jr < 4; ++jr) {
            const int q = qb + t * 16 + g4 * 4 + jr;
            #pragma unroll
            for (int ot = 0; ot < 8; ++ot)
                out[(size_t)q * 128 + ot * 16 + l15] = acc[t][ot][jr] + bvec[ot * 16 + l15];
        }
    }
#undef STAGE
#undef SEXPR
#undef PVX
#undef Z4
}

extern "C" void kernel_launch(void* const* d_in, const int* in_sizes, int n_in,
                              void* d_out, int out_size, void* d_ws, size_t ws_size,
                              hipStream_t stream) {
    (void)in_sizes; (void)n_in; (void)out_size; (void)ws_size;
    const float* x       = (const float*)d_in[0];
    const float* centers = (const float*)d_in[1];
    const float* sigmas  = (const float*)d_in[2];
    const float* W       = (const float*)d_in[3];
    const float* b       = (const float*)d_in[4];
    float* out = (float*)d_out;

    char*  cfrag8 = (char*)d_ws;                     // 16384 slots * 16B = 256 KB
    short* wfrag  = (short*)(cfrag8 + 16384 * 16);   // 16384 slots * 16B = 256 KB
    float* nscsp  = (float*)(wfrag + 16384 * 8);     // 4 KB
    float* tsp    = nscsp + 1024;                    // 4 KB

    rbf_prep<<<384, 256, 0, stream>>>(centers, sigmas, W, cfrag8, wfrag, nscsp, tsp);
    rbf_main<<<512, 256, 0, stream>>>(x, b, cfrag8, wfrag, nscsp, tsp, out);
}